// Round 6
// baseline (435.681 us; speedup 1.0000x reference)
//
#include <hip/hip_runtime.h>
#include <hip/hip_fp16.h>

typedef _Float16 half8 __attribute__((ext_vector_type(8)));
typedef float floatx4 __attribute__((ext_vector_type(4)));

// wperm layout (halfs): hi at [0, WLO_OFF), lo at [WLO_OFF, 2*WLO_OFF)
#define WLO_OFF (6 * 512 * 512)
#define WSTRIDE ((size_t)(8 * 16 * 2048))  // per-W-matrix stride in halfs

// ---------------------------------------------------------------------------
// P1: 6 W matrices [512(k) x 512(n)] fp32 -> fp16 hi + lo (lo = fp16(W - hi),
// ~22-bit effective mantissa), MFMA B-fragment order: tile(w, nt, ki) is
// 4096 B; chunk (u,l) at u*1024 + l*16 holds B[k0+8*(l>>4)+j][n0+16u+(l&15)].
// ---------------------------------------------------------------------------
__global__ __launch_bounds__(256) void permute_w(
    const float* __restrict__ Wir, const float* __restrict__ Whr,
    const float* __restrict__ Wiz, const float* __restrict__ Whz,
    const float* __restrict__ Win, const float* __restrict__ Whn,
    _Float16* __restrict__ wperm) {
  __shared__ __align__(16) float tile[32 * 68];
  const int b = blockIdx.x;
  const int w = b >> 7;
  const int rem = b & 127;
  const int ki = rem >> 3;
  const int nt = rem & 7;
  const float* W = (w == 0) ? Wir : (w == 1) ? Whr : (w == 2) ? Wiz
                 : (w == 3) ? Whz : (w == 4) ? Win : Whn;
  const int k0 = ki * 32, n0 = nt * 64;
  const int t = threadIdx.x;

  const int kk = t >> 3;
  const int nn = (t & 7) * 8;
  const float* src = W + (k0 + kk) * 512 + n0 + nn;
  float4 f0 = *(const float4*)(src);
  float4 f1 = *(const float4*)(src + 4);
  float* drow = tile + kk * 68 + nn;
  *(float4*)(drow) = f0;
  *(float4*)(drow + 4) = f1;
  __syncthreads();

  const int u = t >> 6, l = t & 63;
  const int nloc = 16 * u + (l & 15);
  const int kbase = 8 * (l >> 4);
  half8 vh, vl;
#pragma unroll
  for (int j = 0; j < 8; ++j) {
    float f = tile[(kbase + j) * 68 + nloc];
    _Float16 hiv = (_Float16)f;
    vh[j] = hiv;
    vl[j] = (_Float16)(f - (float)hiv);
  }
  const size_t off = ((size_t)((w * 8 + nt) * 16 + ki)) * 2048 + t * 8;
  *(half8*)(wperm + off) = vh;
  *(half8*)(wperm + WLO_OFF + off) = vl;
}

__device__ __forceinline__ void cvt_hilo(const float4 a, const float4 b,
                                         half8& hi, half8& lo) {
  const float v[8] = {a.x, a.y, a.z, a.w, b.x, b.y, b.z, b.w};
#pragma unroll
  for (int j = 0; j < 8; ++j) {
    _Float16 hv = (_Float16)v[j];
    hi[j] = hv;
    lo[j] = (_Float16)(v[j] - (float)hv);
  }
}

// ---------------------------------------------------------------------------
// R6: BARRIER-FREE, LDS-FREE fused GRU.
// R2/R4/R5 triangulated the binder: W-fragment load latency inside a
// barrier-paired K-loop (the m97 structural stall) at 2 waves/SIMD. Fix:
// eliminate the K-loop barriers entirely. The A operand of 16x16x32_f16 is
// 8 CONSECUTIVE k per lane -> each wave gathers its own A fragments straight
// from row-major fp32 global (2 float4/lane/tile, 100% line utilization) and
// converts hi/lo in-register. B comes pre-permuted from wperm (coalesced).
// No __shared__, no __syncthreads -> no vmcnt(0) drains; the compiler
// pipelines loads across kt iterations with fine-grained per-use waitcnts.
// Cost: A global reads x2 (wn-pair duplication, L2-served) + cvt VALU x2 -
// both pipes were <25% busy.
// Wave tile 64x32; block 4 waves = 128x64; grid 1024.
// ---------------------------------------------------------------------------
__global__ __launch_bounds__(256, 2) void gru_fused(
    const float* __restrict__ x, const float* __restrict__ h,
    const _Float16* __restrict__ wperm,
    const float* __restrict__ br, const float* __restrict__ bz,
    const float* __restrict__ bn, float* __restrict__ out) {
  const int t = threadIdx.x;
  const int lane = t & 63;
  const int wv = t >> 6;
  const int wm = wv >> 1;
  const int wn = wv & 1;
  const int bid = blockIdx.x;
  // mt-grouped swizzle (R5): each XCD owns a set of mt strips; the 8
  // nt-siblings of an mt run adjacently on one XCD -> x/h rows L2-resident.
  const int xcd = bid & 7;
  const int uu = bid >> 3;
  const int nt = uu & 7;
  const int mt = ((uu >> 3) << 3) | xcd;
  const int m0 = mt * 128;
  const int n0 = nt * 64;
  const _Float16* whi = wperm;
  const _Float16* wlo = wperm + WLO_OFF;

  // A-fragment addressing: lane holds A[m = base_i + (lane&15)][k0 + koff + j]
  const int mrow = lane & 15;
  const int koff = 8 * (lane >> 4);
  const float* pax[4];
  const float* pah[4];
#pragma unroll
  for (int i = 0; i < 4; ++i) {
    const size_t roff = (size_t)(m0 + wm * 64 + i * 16 + mrow) * 512 + koff;
    pax[i] = x + roff;
    pah[i] = h + roff;
  }

  floatx4 acc_r[4][2] = {};
  floatx4 acc_z[4][2] = {};
  floatx4 acc_in[4][2] = {};
  floatx4 acc_hn[4][2] = {};

  for (int kt = 0; kt < 16; ++kt) {
    const int kb = kt * 32;

    // --- gather + convert this wave's A fragments (hi & lo) ---
    half8 axh[4], axl[4], ahh[4], ahl[4];
#pragma unroll
    for (int i = 0; i < 4; ++i) {
      float4 a0 = *(const float4*)(pax[i] + kb);
      float4 a1 = *(const float4*)(pax[i] + kb + 4);
      float4 b0 = *(const float4*)(pah[i] + kb);
      float4 b1 = *(const float4*)(pah[i] + kb + 4);
      cvt_hilo(a0, a1, axh[i], axl[i]);
      cvt_hilo(b0, b1, ahh[i], ahl[i]);
    }

    // --- phase 1: B_hi x (A_hi + A_lo) : 96 MFMA ---
#pragma unroll
    for (int jn = 0; jn < 2; ++jn) {
      const int bo = (wn * 2 + jn) * 512 + lane * 8;
      const size_t tb = ((size_t)(nt * 16 + kt)) * 2048 + bo;
      half8 bh_ir = *(const half8*)(whi + tb + 0 * WSTRIDE);
      half8 bh_hr = *(const half8*)(whi + tb + 1 * WSTRIDE);
      half8 bh_iz = *(const half8*)(whi + tb + 2 * WSTRIDE);
      half8 bh_hz = *(const half8*)(whi + tb + 3 * WSTRIDE);
      half8 bh_in = *(const half8*)(whi + tb + 4 * WSTRIDE);
      half8 bh_hn = *(const half8*)(whi + tb + 5 * WSTRIDE);
#pragma unroll
      for (int i = 0; i < 4; ++i) {
        acc_r[i][jn]  = __builtin_amdgcn_mfma_f32_16x16x32_f16(axh[i], bh_ir, acc_r[i][jn], 0, 0, 0);
        acc_r[i][jn]  = __builtin_amdgcn_mfma_f32_16x16x32_f16(axl[i], bh_ir, acc_r[i][jn], 0, 0, 0);
        acc_r[i][jn]  = __builtin_amdgcn_mfma_f32_16x16x32_f16(ahh[i], bh_hr, acc_r[i][jn], 0, 0, 0);
        acc_r[i][jn]  = __builtin_amdgcn_mfma_f32_16x16x32_f16(ahl[i], bh_hr, acc_r[i][jn], 0, 0, 0);
        acc_z[i][jn]  = __builtin_amdgcn_mfma_f32_16x16x32_f16(axh[i], bh_iz, acc_z[i][jn], 0, 0, 0);
        acc_z[i][jn]  = __builtin_amdgcn_mfma_f32_16x16x32_f16(axl[i], bh_iz, acc_z[i][jn], 0, 0, 0);
        acc_z[i][jn]  = __builtin_amdgcn_mfma_f32_16x16x32_f16(ahh[i], bh_hz, acc_z[i][jn], 0, 0, 0);
        acc_z[i][jn]  = __builtin_amdgcn_mfma_f32_16x16x32_f16(ahl[i], bh_hz, acc_z[i][jn], 0, 0, 0);
        acc_in[i][jn] = __builtin_amdgcn_mfma_f32_16x16x32_f16(axh[i], bh_in, acc_in[i][jn], 0, 0, 0);
        acc_in[i][jn] = __builtin_amdgcn_mfma_f32_16x16x32_f16(axl[i], bh_in, acc_in[i][jn], 0, 0, 0);
        acc_hn[i][jn] = __builtin_amdgcn_mfma_f32_16x16x32_f16(ahh[i], bh_hn, acc_hn[i][jn], 0, 0, 0);
        acc_hn[i][jn] = __builtin_amdgcn_mfma_f32_16x16x32_f16(ahl[i], bh_hn, acc_hn[i][jn], 0, 0, 0);
      }
    }

    // --- phase 2: A_hi x B_lo : 48 MFMA (A_lo dead here -> lower reg peak) ---
#pragma unroll
    for (int jn = 0; jn < 2; ++jn) {
      const int bo = (wn * 2 + jn) * 512 + lane * 8;
      const size_t tb = ((size_t)(nt * 16 + kt)) * 2048 + bo;
      half8 bl_ir = *(const half8*)(wlo + tb + 0 * WSTRIDE);
      half8 bl_hr = *(const half8*)(wlo + tb + 1 * WSTRIDE);
      half8 bl_iz = *(const half8*)(wlo + tb + 2 * WSTRIDE);
      half8 bl_hz = *(const half8*)(wlo + tb + 3 * WSTRIDE);
      half8 bl_in = *(const half8*)(wlo + tb + 4 * WSTRIDE);
      half8 bl_hn = *(const half8*)(wlo + tb + 5 * WSTRIDE);
#pragma unroll
      for (int i = 0; i < 4; ++i) {
        acc_r[i][jn]  = __builtin_amdgcn_mfma_f32_16x16x32_f16(axh[i], bl_ir, acc_r[i][jn], 0, 0, 0);
        acc_r[i][jn]  = __builtin_amdgcn_mfma_f32_16x16x32_f16(ahh[i], bl_hr, acc_r[i][jn], 0, 0, 0);
        acc_z[i][jn]  = __builtin_amdgcn_mfma_f32_16x16x32_f16(axh[i], bl_iz, acc_z[i][jn], 0, 0, 0);
        acc_z[i][jn]  = __builtin_amdgcn_mfma_f32_16x16x32_f16(ahh[i], bl_hz, acc_z[i][jn], 0, 0, 0);
        acc_in[i][jn] = __builtin_amdgcn_mfma_f32_16x16x32_f16(axh[i], bl_in, acc_in[i][jn], 0, 0, 0);
        acc_hn[i][jn] = __builtin_amdgcn_mfma_f32_16x16x32_f16(ahh[i], bl_hn, acc_hn[i][jn], 0, 0, 0);
      }
    }
  }

  // --- epilogue: gates + h_new. C/D layout: col = lane&15, row = quad*4+reg ---
  const int quad = lane >> 4;
  const int col = lane & 15;
#pragma unroll
  for (int i = 0; i < 4; ++i) {
    const int mbase = m0 + wm * 64 + i * 16 + quad * 4;
#pragma unroll
    for (int jn = 0; jn < 2; ++jn) {
      const int n = n0 + wn * 32 + jn * 16 + col;
      const float vbr = br[n], vbz = bz[n], vbn = bn[n];
#pragma unroll
      for (int r = 0; r < 4; ++r) {
        const int m = mbase + r;
        const float gr = acc_r[i][jn][r] + vbr;
        const float gz = acc_z[i][jn][r] + vbz;
        const float rg = 1.0f / (1.0f + __expf(-gr));
        const float zg = 1.0f / (1.0f + __expf(-gz));
        const float gn = acc_in[i][jn][r] + rg * acc_hn[i][jn][r] + vbn;
        const float e2 = __expf(2.0f * gn);
        const float ntv = 1.0f - 2.0f / (e2 + 1.0f);
        const float hp = h[(size_t)m * 512 + n];
        out[(size_t)m * 512 + n] = (1.0f - zg) * ntv + zg * hp;
      }
    }
  }
}

extern "C" void kernel_launch(void* const* d_in, const int* in_sizes, int n_in,
                              void* d_out, int out_size, void* d_ws, size_t ws_size,
                              hipStream_t stream) {
  const float* x   = (const float*)d_in[0];
  const float* h   = (const float*)d_in[1];
  const float* Wir = (const float*)d_in[2];
  const float* Whr = (const float*)d_in[3];
  const float* br  = (const float*)d_in[4];
  const float* Wiz = (const float*)d_in[5];
  const float* Whz = (const float*)d_in[6];
  const float* bz  = (const float*)d_in[7];
  const float* Win = (const float*)d_in[8];
  const float* Whn = (const float*)d_in[9];
  const float* bn  = (const float*)d_in[10];
  float* out = (float*)d_out;
  _Float16* wperm = (_Float16*)d_ws;  // needs 2 * 6*512*512*2 = 6.3 MB

  permute_w<<<768, 256, 0, stream>>>(Wir, Whr, Wiz, Whz, Win, Whn, wperm);
  gru_fused<<<1024, 256, 0, stream>>>(x, h, wperm, br, bz, bn, out);
}

// Round 7
// 405.705 us; speedup vs baseline: 1.0739x; 1.0739x over previous
//
#include <hip/hip_runtime.h>
#include <hip/hip_fp16.h>

typedef _Float16 half8 __attribute__((ext_vector_type(8)));
typedef float floatx4 __attribute__((ext_vector_type(4)));

// wperm layout (halfs): hi at [0, WLO_OFF), lo at [WLO_OFF, 2*WLO_OFF)
#define WLO_OFF (6 * 512 * 512)
#define WSTRIDE ((size_t)(8 * 16 * 2048))  // per-W-matrix stride in halfs

#define MFMA16(acc, a, b) \
  acc = __builtin_amdgcn_mfma_f32_16x16x32_f16(a, b, acc, 0, 0, 0)

// ---------------------------------------------------------------------------
// P1: 6 W matrices [512(k) x 512(n)] fp32 -> fp16 hi + lo (lo = fp16(W - hi),
// ~22-bit effective mantissa), MFMA B-fragment order: tile(w, nt, ki) is
// 4096 B; chunk (u,l) at u*1024 + l*16 holds B[k0+8*(l>>4)+j][n0+16u+(l&15)].
// ---------------------------------------------------------------------------
__global__ __launch_bounds__(256) void permute_w(
    const float* __restrict__ Wir, const float* __restrict__ Whr,
    const float* __restrict__ Wiz, const float* __restrict__ Whz,
    const float* __restrict__ Win, const float* __restrict__ Whn,
    _Float16* __restrict__ wperm) {
  __shared__ __align__(16) float tile[32 * 68];
  const int b = blockIdx.x;
  const int w = b >> 7;
  const int rem = b & 127;
  const int ki = rem >> 3;
  const int nt = rem & 7;
  const float* W = (w == 0) ? Wir : (w == 1) ? Whr : (w == 2) ? Wiz
                 : (w == 3) ? Whz : (w == 4) ? Win : Whn;
  const int k0 = ki * 32, n0 = nt * 64;
  const int t = threadIdx.x;

  const int kk = t >> 3;
  const int nn = (t & 7) * 8;
  const float* src = W + (k0 + kk) * 512 + n0 + nn;
  float4 f0 = *(const float4*)(src);
  float4 f1 = *(const float4*)(src + 4);
  float* drow = tile + kk * 68 + nn;
  *(float4*)(drow) = f0;
  *(float4*)(drow + 4) = f1;
  __syncthreads();

  const int u = t >> 6, l = t & 63;
  const int nloc = 16 * u + (l & 15);
  const int kbase = 8 * (l >> 4);
  half8 vh, vl;
#pragma unroll
  for (int j = 0; j < 8; ++j) {
    float f = tile[(kbase + j) * 68 + nloc];
    _Float16 hiv = (_Float16)f;
    vh[j] = hiv;
    vl[j] = (_Float16)(f - (float)hiv);
  }
  const size_t off = ((size_t)((w * 8 + nt) * 16 + ki)) * 2048 + t * 8;
  *(half8*)(wperm + off) = vh;
  *(half8*)(wperm + WLO_OFF + off) = vl;
}

__device__ __forceinline__ void cvt_hilo(const float4 a, const float4 b,
                                         half8& hi, half8& lo) {
  const float v[8] = {a.x, a.y, a.z, a.w, b.x, b.y, b.z, b.w};
#pragma unroll
  for (int j = 0; j < 8; ++j) {
    _Float16 hv = (_Float16)v[j];
    hi[j] = hv;
    lo[j] = (_Float16)(v[j] - (float)hv);
  }
}

// ---------------------------------------------------------------------------
// R7: barrier-free, LDS-free, LOW-PRESSURE fused GRU.
// Evidence through R6: effective ~18 cyc/MFMA (vs 4.8 achievable) = pipe
// stalls from (a) 4-deep dependent MFMA chains on the same accumulator and
// (b) 244-256 live regs leaving the scheduler zero slack to hoist loads or
// pipeline across kt. Fix:
//  - wave tile 64(m) x 16(n): acc = 4 gates x 16 = 64 VGPR (was 128);
//    total live ~200-240 -> ~50 regs of scheduler slack.
//  - next-kt A raw prefetch issued at TOP of the MFMA block (72 MFMAs of
//    cover), hi/lo cvt at the tail.
//  - MFMA order hand-interleaved: same-acc reuse distance >= 8.
//  - 1-wave blocks (64 thr), grid 8192: waves free-run, no barriers at all.
//  - swizzle: 64-row A strip owned by one XCD; its 32 n-slices adjacent.
// ---------------------------------------------------------------------------
__global__ __launch_bounds__(64, 2) void gru_fused(
    const float* __restrict__ x, const float* __restrict__ h,
    const _Float16* __restrict__ wperm,
    const float* __restrict__ br, const float* __restrict__ bz,
    const float* __restrict__ bn, float* __restrict__ out) {
  const int lane = threadIdx.x;
  const int bid = blockIdx.x;
  // swizzle: xcd = bid&7 (HW round-robin). strip = ((v>>5)<<3)|xcd owns rows
  // [strip*64, +64); nn16 = v&31 spans the 32 16-col slices adjacent in time.
  const int xcd = bid & 7;
  const int v = bid >> 3;
  const int nn16 = v & 31;
  const int strip = ((v >> 5) << 3) | xcd;  // 0..255
  const int m0 = strip * 64;
  const int nt = nn16 >> 2;        // 64-col wperm tile
  const int u16 = nn16 & 3;        // 16-col sub-tile
  const int n0 = nn16 * 16;
  const _Float16* whi = wperm;
  const _Float16* wlo = wperm + WLO_OFF;

  // A-fragment addressing: lane holds A[m0 + i*16 + (lane&15)][koff + j]
  const int mrow = lane & 15;
  const int koff = 8 * (lane >> 4);
  const float* pax[4];
  const float* pah[4];
#pragma unroll
  for (int i = 0; i < 4; ++i) {
    const size_t roff = (size_t)(m0 + i * 16 + mrow) * 512 + koff;
    pax[i] = x + roff;
    pah[i] = h + roff;
  }
  const int bo = u16 * 512 + lane * 8;

  floatx4 acc_r[4] = {};
  floatx4 acc_z[4] = {};
  floatx4 acc_in[4] = {};
  floatx4 acc_hn[4] = {};

  // preload kt=0 A fragments
  half8 axh[4], axl[4], ahh[4], ahl[4];
#pragma unroll
  for (int i = 0; i < 4; ++i) {
    cvt_hilo(*(const float4*)(pax[i]), *(const float4*)(pax[i] + 4), axh[i], axl[i]);
    cvt_hilo(*(const float4*)(pah[i]), *(const float4*)(pah[i] + 4), ahh[i], ahl[i]);
  }

  for (int kt = 0; kt < 16; ++kt) {
    const size_t tb = ((size_t)(nt * 16 + kt)) * 2048 + bo;
    // B-hi loads (needed first)
    half8 bh_ir = *(const half8*)(whi + tb + 0 * WSTRIDE);
    half8 bh_hr = *(const half8*)(whi + tb + 1 * WSTRIDE);
    half8 bh_iz = *(const half8*)(whi + tb + 2 * WSTRIDE);
    half8 bh_hz = *(const half8*)(whi + tb + 3 * WSTRIDE);
    half8 bh_in = *(const half8*)(whi + tb + 4 * WSTRIDE);
    half8 bh_hn = *(const half8*)(whi + tb + 5 * WSTRIDE);
    // next-kt A raw prefetch: 16 loads, consumed only at the tail cvt.
    const int kbn = ((kt + 1) & 15) * 32;
    float4 nrx[8], nrh[8];
#pragma unroll
    for (int i = 0; i < 4; ++i) {
      nrx[2 * i]     = *(const float4*)(pax[i] + kbn);
      nrx[2 * i + 1] = *(const float4*)(pax[i] + kbn + 4);
      nrh[2 * i]     = *(const float4*)(pah[i] + kbn);
      nrh[2 * i + 1] = *(const float4*)(pah[i] + kbn + 4);
    }

    // ---- phase 1: B_hi x (A_hi + A_lo), 48 MFMA, acc-distance >= 8 ----
#pragma unroll
    for (int i = 0; i < 4; ++i) { MFMA16(acc_r[i], axh[i], bh_ir); MFMA16(acc_z[i], axh[i], bh_iz); }
#pragma unroll
    for (int i = 0; i < 4; ++i) { MFMA16(acc_r[i], ahh[i], bh_hr); MFMA16(acc_z[i], ahh[i], bh_hz); }
#pragma unroll
    for (int i = 0; i < 4; ++i) { MFMA16(acc_in[i], axh[i], bh_in); MFMA16(acc_hn[i], ahh[i], bh_hn); }
#pragma unroll
    for (int i = 0; i < 4; ++i) { MFMA16(acc_r[i], axl[i], bh_ir); MFMA16(acc_z[i], axl[i], bh_iz); }
#pragma unroll
    for (int i = 0; i < 4; ++i) { MFMA16(acc_r[i], ahl[i], bh_hr); MFMA16(acc_z[i], ahl[i], bh_hz); }
#pragma unroll
    for (int i = 0; i < 4; ++i) { MFMA16(acc_in[i], axl[i], bh_in); MFMA16(acc_hn[i], ahl[i], bh_hn); }

    // ---- phase 2: B_lo x A_hi, 24 MFMA ----
    half8 bl_ir = *(const half8*)(wlo + tb + 0 * WSTRIDE);
    half8 bl_hr = *(const half8*)(wlo + tb + 1 * WSTRIDE);
    half8 bl_iz = *(const half8*)(wlo + tb + 2 * WSTRIDE);
    half8 bl_hz = *(const half8*)(wlo + tb + 3 * WSTRIDE);
    half8 bl_in = *(const half8*)(wlo + tb + 4 * WSTRIDE);
    half8 bl_hn = *(const half8*)(wlo + tb + 5 * WSTRIDE);
#pragma unroll
    for (int i = 0; i < 4; ++i) { MFMA16(acc_r[i], axh[i], bl_ir); MFMA16(acc_z[i], axh[i], bl_iz); }
#pragma unroll
    for (int i = 0; i < 4; ++i) { MFMA16(acc_r[i], ahh[i], bl_hr); MFMA16(acc_z[i], ahh[i], bl_hz); }
#pragma unroll
    for (int i = 0; i < 4; ++i) { MFMA16(acc_in[i], axh[i], bl_in); MFMA16(acc_hn[i], ahh[i], bl_hn); }

    // ---- tail: convert prefetched A for kt+1 ----
#pragma unroll
    for (int i = 0; i < 4; ++i) {
      cvt_hilo(nrx[2 * i], nrx[2 * i + 1], axh[i], axl[i]);
      cvt_hilo(nrh[2 * i], nrh[2 * i + 1], ahh[i], ahl[i]);
    }
  }

  // --- epilogue: gates + h_new. C/D layout: col = lane&15, row = quad*4+reg ---
  const int quad = lane >> 4;
  const int col = lane & 15;
  const int n = n0 + col;
  const float vbr = br[n], vbz = bz[n], vbn = bn[n];
#pragma unroll
  for (int i = 0; i < 4; ++i) {
    const int mbase = m0 + i * 16 + quad * 4;
#pragma unroll
    for (int r = 0; r < 4; ++r) {
      const int m = mbase + r;
      const float gr = acc_r[i][r] + vbr;
      const float gz = acc_z[i][r] + vbz;
      const float rg = 1.0f / (1.0f + __expf(-gr));
      const float zg = 1.0f / (1.0f + __expf(-gz));
      const float gn = acc_in[i][r] + rg * acc_hn[i][r] + vbn;
      const float e2 = __expf(2.0f * gn);
      const float ntv = 1.0f - 2.0f / (e2 + 1.0f);
      const float hp = h[(size_t)m * 512 + n];
      out[(size_t)m * 512 + n] = (1.0f - zg) * ntv + zg * hp;
    }
  }
}

extern "C" void kernel_launch(void* const* d_in, const int* in_sizes, int n_in,
                              void* d_out, int out_size, void* d_ws, size_t ws_size,
                              hipStream_t stream) {
  const float* x   = (const float*)d_in[0];
  const float* h   = (const float*)d_in[1];
  const float* Wir = (const float*)d_in[2];
  const float* Whr = (const float*)d_in[3];
  const float* br  = (const float*)d_in[4];
  const float* Wiz = (const float*)d_in[5];
  const float* Whz = (const float*)d_in[6];
  const float* bz  = (const float*)d_in[7];
  const float* Win = (const float*)d_in[8];
  const float* Whn = (const float*)d_in[9];
  const float* bn  = (const float*)d_in[10];
  float* out = (float*)d_out;
  _Float16* wperm = (_Float16*)d_ws;  // needs 2 * 6*512*512*2 = 6.3 MB

  permute_w<<<768, 256, 0, stream>>>(Wir, Whr, Wiz, Whz, Win, Whn, wperm);
  gru_fused<<<8192, 64, 0, stream>>>(x, h, wperm, br, bz, bn, out);
}